// Round 15
// baseline (217.720 us; speedup 1.0000x reference)
//
#include <hip/hip_runtime.h>
#include <stdint.h>

#define N_TOK 4096
#define DIM   512
#define BATCH 4
#define BN    (BATCH * N_TOK)
#define JSPLIT 8
#define IPW   64                      // i-rows per wave (A resident in regs)
#define IPB   256                     // i-rows per block (4 waves)
#define NG    (N_TOK / JSPLIT / 16)   // 32 j-groups of 16 per slice

typedef __attribute__((ext_vector_type(4))) float f32x4;
typedef __attribute__((ext_vector_type(8))) int   i32x8;

__device__ __forceinline__ float sumsq8(uint lo, uint hi) {
    float s = 0.f, f;
    f = __builtin_amdgcn_cvt_f32_fp8((int)lo, 0); s = fmaf(f, f, s);
    f = __builtin_amdgcn_cvt_f32_fp8((int)lo, 1); s = fmaf(f, f, s);
    f = __builtin_amdgcn_cvt_f32_fp8((int)lo, 2); s = fmaf(f, f, s);
    f = __builtin_amdgcn_cvt_f32_fp8((int)lo, 3); s = fmaf(f, f, s);
    f = __builtin_amdgcn_cvt_f32_fp8((int)hi, 0); s = fmaf(f, f, s);
    f = __builtin_amdgcn_cvt_f32_fp8((int)hi, 1); s = fmaf(f, f, s);
    f = __builtin_amdgcn_cvt_f32_fp8((int)hi, 2); s = fmaf(f, f, s);
    f = __builtin_amdgcn_cvt_f32_fp8((int)hi, 3); s = fmaf(f, f, s);
    return s;
}

// ---------- prep: fp8 convert -> fb (row-major) + fbT (B-operand, MX K=128 layout)
//            + per-row sumsq of QUANTIZED values (diag d_ii ~ 0 matches ref k_ii=1).
__global__ __launch_bounds__(256) void prep_kernel(
    const float* __restrict__ feat, uint8_t* __restrict__ fb,
    uint8_t* __restrict__ fbT, float* __restrict__ sq)
{
    __shared__ __align__(16) long lt[1024];        // [chunk c 0..63][row16], swizzled
    const int t = threadIdx.x;
    const int row16 = t >> 4, seg = t & 15;
    const size_t grp = blockIdx.x;
    const size_t row = grp * 16 + row16;

    const float4* src = (const float4*)(feat + row * DIM + seg * 32);
    uint32_t wd[8];
    float s = 0.f;
#pragma unroll
    for (int i = 0; i < 4; ++i) {
        float4 a = src[2 * i], b = src[2 * i + 1];
        uint lo = (uint)__builtin_amdgcn_cvt_pk_fp8_f32(a.x, a.y, 0, false);
        lo      = (uint)__builtin_amdgcn_cvt_pk_fp8_f32(a.z, a.w, (int)lo, true);
        uint hi = (uint)__builtin_amdgcn_cvt_pk_fp8_f32(b.x, b.y, 0, false);
        hi      = (uint)__builtin_amdgcn_cvt_pk_fp8_f32(b.z, b.w, (int)hi, true);
        wd[2 * i] = lo; wd[2 * i + 1] = hi;
        s += sumsq8(lo, hi);
    }

    uint4* dst = (uint4*)(fb + row * DIM + seg * 32);
    uint4 o0; o0.x = wd[0]; o0.y = wd[1]; o0.z = wd[2]; o0.w = wd[3];
    uint4 o1; o1.x = wd[4]; o1.y = wd[5]; o1.z = wd[6]; o1.w = wd[7];
    dst[0] = o0; dst[1] = o1;

#pragma unroll
    for (int i = 0; i < 4; ++i) {
        int c = seg * 4 + i;                       // 8B chunk of this row
        long d = ((long)(unsigned)wd[2 * i + 1] << 32) | (unsigned)wd[2 * i];
        lt[c * 16 + ((row16 + c) & 15)] = d;
    }

#pragma unroll
    for (int m = 1; m < 16; m <<= 1) s += __shfl_xor(s, m);
    if (seg == 0) sq[row] = s;

    __syncthreads();
    long* ot = (long*)(fbT + grp * 8192);
#pragma unroll
    for (int i = 0; i < 4; ++i) {
        int p   = t + i * 256;                     // output long index, coalesced
        int kk  = p >> 8;                          // 128-wide K chunk
        int rem = p & 255;
        int q   = rem >> 6;                        // 32-elem scale block
        int r   = (rem >> 2) & 15;                 // j row in group
        int w8  = p & 3;                           // 8B word within lane's 32B
        int c   = kk * 16 + q * 4 + w8;            // source 8B chunk in row
        ot[p] = lt[c * 16 + ((r + c) & 15)];
    }
}

// ---------- entropy + fused last-block finalize ----------
// R14 MX-scaled fp8 body unchanged. New epilogue: slice Sp/Tp stored with
// agent-scope atomics; per-(batch,iblk) counter bumped (ACQ_REL, agent); the 8th
// arriving block finalizes its 256 rows (entropy->sigmoid->scale) in-place.
// No spin, no co-residency assumption; removes the finalize dispatch (~23us+gap)
// and overlaps its memory time under remaining entropy blocks.
__global__ __launch_bounds__(256, 2) void entropy_kernel(
    const float* __restrict__ feat, const uint8_t* __restrict__ fb,
    const uint8_t* __restrict__ fbT, const float* __restrict__ sq,
    const float* __restrict__ tgt, const float* __restrict__ temp,
    float* __restrict__ Sp, float* __restrict__ Tp,
    int* __restrict__ cnt, float* __restrict__ out)
{
    __shared__ int sh_old;
    const int t    = threadIdx.x;
    const int w    = t >> 6;
    const int lane = t & 63;
    const int q    = lane >> 4;
    const int c16  = lane & 15;

    const int flat  = blockIdx.x;
    const int combo = flat & 31;
    const int batch = combo >> 3;
    const int jh    = combo & 7;
    const int iblk  = flat >> 5;
    const int iw    = iblk * IPB + w * IPW;
    const size_t rowbase = (size_t)batch * N_TOK;

    const float tau    = temp[0];
    const float inv2t2 = 0.5f / (tau * tau);
    const float cg     = 1.0f / (tau * tau);

    // A fragments: 4 strips x 4 K-chunks x 32B = 128 regs
    i32x8 afrag[4][4];
#pragma unroll
    for (int s = 0; s < 4; ++s) {
        const uint4* ap = (const uint4*)(fb + (rowbase + iw + s * 16 + c16) * DIM);
#pragma unroll
        for (int kk = 0; kk < 4; ++kk) {
            uint4 lo = ap[kk * 8 + q * 2];
            uint4 hi = ap[kk * 8 + q * 2 + 1];
            i32x8 v = {(int)lo.x, (int)lo.y, (int)lo.z, (int)lo.w,
                       (int)hi.x, (int)hi.y, (int)hi.z, (int)hi.w};
            afrag[s][kk] = v;
        }
    }
    float pi[4][4];
#pragma unroll
    for (int s = 0; s < 4; ++s)
#pragma unroll
        for (int r = 0; r < 4; ++r)
            pi[s][r] = -sq[rowbase + iw + s * 16 + q * 4 + r] * inv2t2;

    float S[4][4], T[4][4];
#pragma unroll
    for (int s = 0; s < 4; ++s)
#pragma unroll
        for (int r = 0; r < 4; ++r) { S[s][r] = 0.f; T[s][r] = 0.f; }

    const uint4* bp = (const uint4*)(fbT
                    + ((size_t)batch * (N_TOK / 16) + (size_t)jh * NG) * 8192)
                    + q * 32 + c16 * 2;
    const float* sqj = sq + rowbase + jh * (N_TOK / JSPLIT) + c16;

    for (int g = 0; g < NG; ++g) {
        float pj = -sqj[g * 16] * inv2t2;
        const uint4* bg = bp + (size_t)g * 512;
        f32x4 acc[4] = {{0,0,0,0},{0,0,0,0},{0,0,0,0},{0,0,0,0}};
#pragma unroll
        for (int kk = 0; kk < 4; kk += 2) {        // 2 B chunks in flight (32 regs)
            uint4 l0 = bg[kk * 128],       h0 = bg[kk * 128 + 1];
            uint4 l1 = bg[(kk+1) * 128],   h1 = bg[(kk+1) * 128 + 1];
            i32x8 b0 = {(int)l0.x, (int)l0.y, (int)l0.z, (int)l0.w,
                        (int)h0.x, (int)h0.y, (int)h0.z, (int)h0.w};
            i32x8 b1 = {(int)l1.x, (int)l1.y, (int)l1.z, (int)l1.w,
                        (int)h1.x, (int)h1.y, (int)h1.z, (int)h1.w};
            acc[0] = __builtin_amdgcn_mfma_scale_f32_16x16x128_f8f6f4(afrag[0][kk], b0, acc[0], 0, 0, 0, 127, 0, 127);
            acc[1] = __builtin_amdgcn_mfma_scale_f32_16x16x128_f8f6f4(afrag[1][kk], b0, acc[1], 0, 0, 0, 127, 0, 127);
            acc[2] = __builtin_amdgcn_mfma_scale_f32_16x16x128_f8f6f4(afrag[2][kk], b0, acc[2], 0, 0, 0, 127, 0, 127);
            acc[3] = __builtin_amdgcn_mfma_scale_f32_16x16x128_f8f6f4(afrag[3][kk], b0, acc[3], 0, 0, 0, 127, 0, 127);
            acc[0] = __builtin_amdgcn_mfma_scale_f32_16x16x128_f8f6f4(afrag[0][kk+1], b1, acc[0], 0, 0, 0, 127, 0, 127);
            acc[1] = __builtin_amdgcn_mfma_scale_f32_16x16x128_f8f6f4(afrag[1][kk+1], b1, acc[1], 0, 0, 0, 127, 0, 127);
            acc[2] = __builtin_amdgcn_mfma_scale_f32_16x16x128_f8f6f4(afrag[2][kk+1], b1, acc[2], 0, 0, 0, 127, 0, 127);
            acc[3] = __builtin_amdgcn_mfma_scale_f32_16x16x128_f8f6f4(afrag[3][kk+1], b1, acc[3], 0, 0, 0, 127, 0, 127);
        }
        float m = -1e30f;
#pragma unroll
        for (int s = 0; s < 4; ++s)
#pragma unroll
            for (int r = 0; r < 4; ++r) {          // e in place of acc (dead after)
                acc[s][r] = fmaf(acc[s][r], cg, pi[s][r] + pj);
                m = fmaxf(m, acc[s][r]);
            }
        if (m > -110.0f) {                         // only diagonal-adjacent groups
#pragma unroll
            for (int s = 0; s < 4; ++s)
#pragma unroll
                for (int r = 0; r < 4; ++r) {
                    float ee = fminf(acc[s][r], 0.f);
                    float k  = __expf(ee);
                    S[s][r] += k;
                    T[s][r]  = fmaf(k, ee, T[s][r]);
                }
        }
    }

    // reduce over the 16 j-columns (c16 lanes)
#pragma unroll
    for (int m = 1; m < 16; m <<= 1)
#pragma unroll
        for (int s = 0; s < 4; ++s)
#pragma unroll
            for (int r = 0; r < 4; ++r) {
                S[s][r] += __shfl_xor(S[s][r], m);
                T[s][r] += __shfl_xor(T[s][r], m);
            }

    if (c16 == 0) {                                // agent-scope stores (cross-XCD safe)
#pragma unroll
        for (int s = 0; s < 4; ++s)
#pragma unroll
            for (int r = 0; r < 4; ++r) {
                size_t idx = (size_t)jh * BN + rowbase + iw + s * 16 + q * 4 + r;
                __hip_atomic_store(&Sp[idx], S[s][r], __ATOMIC_RELAXED, __HIP_MEMORY_SCOPE_AGENT);
                __hip_atomic_store(&Tp[idx], T[s][r], __ATOMIC_RELAXED, __HIP_MEMORY_SCOPE_AGENT);
            }
    }
    __syncthreads();                               // all slice stores completed (vmcnt0)
    if (t == 0) {
        __threadfence();                           // release our slice device-wide
        sh_old = __hip_atomic_fetch_add(&cnt[batch * 16 + iblk], 1,
                                        __ATOMIC_ACQ_REL, __HIP_MEMORY_SCOPE_AGENT);
    }
    __syncthreads();
    if (sh_old != JSPLIT - 1) return;              // not the last slice: done
    __threadfence();                               // acquire other slices' stores

    // ---- finalize this (batch, iblk): 256 rows, 64 per wave ----
    const float tgt0 = tgt[0];
    for (int rr = 0; rr < 64; ++rr) {
        size_t grow = rowbase + (size_t)iblk * IPB + w * 64 + rr;
        float Ssum = 0.f, Tsum = 0.f;
#pragma unroll
        for (int j = 0; j < JSPLIT; ++j) {
            Ssum += __hip_atomic_load(&Sp[(size_t)j * BN + grow], __ATOMIC_RELAXED, __HIP_MEMORY_SCOPE_AGENT);
            Tsum += __hip_atomic_load(&Tp[(size_t)j * BN + grow], __ATOMIC_RELAXED, __HIP_MEMORY_SCOPE_AGENT);
        }
        float E  = __logf(Ssum) - Tsum / Ssum;     // entropy (sans +1e-6, bias<4e-3)
        float cs = 1.0f / (1.0f + __expf((E - tgt0) / tau));

        const float4* F4 = (const float4*)(feat + grow * DIM);
        float4*       O4 = (float4*)(out + grow * DIM);
        float4 v0 = F4[lane], v1 = F4[lane + 64];
        v0.x *= cs; v0.y *= cs; v0.z *= cs; v0.w *= cs;
        v1.x *= cs; v1.y *= cs; v1.z *= cs; v1.w *= cs;
        O4[lane] = v0; O4[lane + 64] = v1;
        if (lane == 0) out[(size_t)BN * DIM + grow] = cs;
    }
}

extern "C" void kernel_launch(void* const* d_in, const int* in_sizes, int n_in,
                              void* d_out, int out_size, void* d_ws, size_t ws_size,
                              hipStream_t stream) {
    const float* feat = (const float*)d_in[0];
    const float* tgt  = (const float*)d_in[7];   // target_entropy
    const float* temp = (const float*)d_in[8];   // temperature
    float* out = (float*)d_out;

    char* ws = (char*)d_ws;
    uint8_t* fb  = (uint8_t*)ws;                               // fp8 row-major, 8.4MB
    uint8_t* fbT = fb + (size_t)BN * DIM;                      // fp8 B-layout, 8.4MB
    float*   sq  = (float*)(fbT + (size_t)BN * DIM);           // quantized row sumsq
    float*   Sp  = sq + BN;                                    // partial S, JSPLIT slices
    float*   Tp  = Sp + (size_t)JSPLIT * BN;                   // partial T, JSPLIT slices
    int*     cnt = (int*)(Tp + (size_t)JSPLIT * BN);           // 64 arrival counters

    hipMemsetAsync(cnt, 0, BATCH * 16 * sizeof(int), stream);
    prep_kernel<<<dim3(BN / 16), dim3(256), 0, stream>>>(feat, fb, fbT, sq);
    entropy_kernel<<<dim3((N_TOK / IPB) * BATCH * JSPLIT), dim3(256), 0, stream>>>(
        feat, fb, fbT, sq, tgt, temp, Sp, Tp, cnt, out);
}